// Round 1
// baseline (4817.565 us; speedup 1.0000x reference)
//
#include <hip/hip_runtime.h>
#include <hip/hip_bf16.h>
#include <stdint.h>

#define HIDDEN 1024
#define FEAT   64
#define BATCH  512
#define SEQ    64
#define GATES  3072        // 3*HIDDEN
#define CHUNK_T 16         // timesteps per gates_x chunk (keeps gx buffer at ~50 MB)

typedef __attribute__((ext_vector_type(4))) float f32x4;
typedef __attribute__((ext_vector_type(8))) short s16x8;   // 8 bf16 = 4 VGPRs (MFMA A/B frag)

__device__ inline unsigned short f2bf(float f) {
    unsigned u = __builtin_bit_cast(unsigned, f);
    u += 0x7fff + ((u >> 16) & 1);          // round-to-nearest-even (finite inputs)
    return (unsigned short)(u >> 16);
}
__device__ inline float bf2f(unsigned short s) {
    unsigned u = ((unsigned)s) << 16;
    return __builtin_bit_cast(float, u);
}

#define GLOAD_LDS16(g, l) __builtin_amdgcn_global_load_lds( \
    (const __attribute__((address_space(1))) unsigned int*)(g), \
    (__attribute__((address_space(3))) unsigned int*)(l), 16, 0, 0)

// ---------------- weight/input conversion ----------------
__global__ void k_convert(const float* __restrict__ src, unsigned short* __restrict__ dst, int n) {
    int i = blockIdx.x * blockDim.x + threadIdx.x;
    if (i < n) dst[i] = f2bf(src[i]);
}

// x (B,T,F) fp32 -> xbf (T,B,F) bf16  (t-major so a chunk of timesteps is GEMM-row-contiguous)
__global__ void k_xpose(const float* __restrict__ x, unsigned short* __restrict__ xbf) {
    int i = blockIdx.x * blockDim.x + threadIdx.x;
    if (i >= BATCH * SEQ * FEAT) return;
    int f = i & 63, t = (i >> 6) & 63, b = i >> 12;
    xbf[((size_t)t * BATCH + b) * FEAT + f] = f2bf(x[i]);
}

// ---------------- BT-form MFMA GEMM: C[m][n] = sum_k A[m][k]*B[n][k] (+bias[n]) ----------------
// A: M x K bf16 row-major, B: N x K bf16 row-major (i.e. weights as stored: (3H, K)).
// 256 threads = 4 waves in 2x2; each wave computes (BM/2)x(BN/2) via 16x16x32 bf16 MFMA.
template<int BM, int BN, int BK, bool STORE_BF16>
__global__ __launch_bounds__(256) void k_gemm_bt(
    const unsigned short* __restrict__ A,
    const unsigned short* __restrict__ B,
    const float* __restrict__ bias,     // nullptr -> no bias
    void* __restrict__ C,
    int K, int ldc)
{
    __shared__ unsigned short As[BM * BK];
    __shared__ unsigned short Bs[BN * BK];
    const int tileN = blockIdx.x * BN;
    const int tileM = blockIdx.y * BM;
    const int wid  = threadIdx.x >> 6;
    const int lane = threadIdx.x & 63;
    constexpr int WM = BM / 2, WN = BN / 2;
    constexpr int FM = WM / 16, FN = WN / 16;
    const int wm0 = (wid >> 1) * WM;
    const int wn0 = (wid & 1) * WN;

    f32x4 acc[FM][FN];
    const f32x4 zero = {0.f, 0.f, 0.f, 0.f};
#pragma unroll
    for (int i = 0; i < FM; ++i)
#pragma unroll
        for (int j = 0; j < FN; ++j) acc[i][j] = zero;

    constexpr int SPR = BK / 8;            // 16B segments per row
    constexpr int RA = BM * SPR / 256;     // staging rounds for A
    constexpr int RB = BN * SPR / 256;

    for (int k0 = 0; k0 < K; k0 += BK) {
        __syncthreads();                   // protect LDS from previous iteration's readers
#pragma unroll
        for (int r = 0; r < RA; ++r) {
            int sbase = r * 256 + wid * 64;        // wave-uniform segment base
            int s = sbase + lane;
            int row = s >> 3, cs = s & (SPR - 1);  // SPR == 8
            const unsigned short* g = A + (size_t)(tileM + row) * K + k0 + cs * 8;
            GLOAD_LDS16(g, As + sbase * 8);
        }
#pragma unroll
        for (int r = 0; r < RB; ++r) {
            int sbase = r * 256 + wid * 64;
            int s = sbase + lane;
            int row = s >> 3, cs = s & (SPR - 1);
            const unsigned short* g = B + (size_t)(tileN + row) * K + k0 + cs * 8;
            GLOAD_LDS16(g, Bs + sbase * 8);
        }
        __syncthreads();                   // drains vmcnt: staged data visible

#pragma unroll
        for (int kk = 0; kk < BK / 32; ++kk) {
            s16x8 a[FM], b[FN];
#pragma unroll
            for (int i = 0; i < FM; ++i)
                a[i] = *(const s16x8*)&As[(wm0 + i * 16 + (lane & 15)) * BK + kk * 32 + (lane >> 4) * 8];
#pragma unroll
            for (int j = 0; j < FN; ++j)
                b[j] = *(const s16x8*)&Bs[(wn0 + j * 16 + (lane & 15)) * BK + kk * 32 + (lane >> 4) * 8];
#pragma unroll
            for (int i = 0; i < FM; ++i)
#pragma unroll
                for (int j = 0; j < FN; ++j)
                    acc[i][j] = __builtin_amdgcn_mfma_f32_16x16x32_bf16(a[i], b[j], acc[i][j], 0, 0, 0);
        }
    }

    // epilogue: C/D layout col = lane&15, row = (lane>>4)*4 + reg  [m89-verified]
    const int r4 = (lane >> 4) * 4;
    const int cn = lane & 15;
#pragma unroll
    for (int i = 0; i < FM; ++i)
#pragma unroll
        for (int j = 0; j < FN; ++j)
#pragma unroll
            for (int r = 0; r < 4; ++r) {
                int row = tileM + wm0 + i * 16 + r4 + r;
                int col = tileN + wn0 + j * 16 + cn;
                float v = acc[i][j][r];
                if (bias) v += bias[col];
                if (STORE_BF16)
                    ((unsigned short*)C)[(size_t)row * ldc + col] = f2bf(v);
                else
                    ((float*)C)[(size_t)row * ldc + col] = v;
            }
}

// ---------------- fused GRU gate elementwise ----------------
// gx rows are (tt*BATCH + b); gh is (BATCH x 3072) from the recurrent GEMM (no bias);
// h (fp32, in-place carry), hout = bf16 h_t written into the t-major sequence buffer.
__global__ void k_gru_elem(const unsigned short* __restrict__ gx,
                           const float* __restrict__ gh,
                           const float* __restrict__ bhh,
                           float* __restrict__ h,
                           unsigned short* __restrict__ hout,
                           int tt, int is_t0)
{
    int i = blockIdx.x * 256 + threadIdx.x;      // BATCH*HIDDEN threads
    int b = i >> 10, j = i & 1023;
    size_t gxi = ((size_t)(tt * BATCH + b)) * GATES + j;
    float xr = bf2f(gx[gxi]);
    float xz = bf2f(gx[gxi + HIDDEN]);
    float xn = bf2f(gx[gxi + 2 * HIDDEN]);
    float hr, hz, hn;
    if (is_t0) {
        hr = bhh[j]; hz = bhh[HIDDEN + j]; hn = bhh[2 * HIDDEN + j];
    } else {
        size_t gi = (size_t)b * GATES + j;
        hr = gh[gi] + bhh[j];
        hz = gh[gi + HIDDEN] + bhh[HIDDEN + j];
        hn = gh[gi + 2 * HIDDEN] + bhh[2 * HIDDEN + j];
    }
    float r = 1.f / (1.f + __expf(-(xr + hr)));
    float z = 1.f / (1.f + __expf(-(xz + hz)));
    float n = tanhf(xn + r * hn);
    float hv = h[i];
    float hnew = (1.f - z) * n + z * hv;
    h[i] = hnew;
    hout[i] = f2bf(hnew);
}

// ---------------- batch-norm over batch: fold to per-unit affine ----------------
__global__ void k_bn_stats(const float* __restrict__ h, const float* __restrict__ gamma,
                           const float* __restrict__ beta, float* __restrict__ a, float* __restrict__ bb)
{
    int j = blockIdx.x * 256 + threadIdx.x;      // HIDDEN threads
    float s = 0.f, q = 0.f;
    for (int b = 0; b < BATCH; ++b) {
        float v = h[(size_t)b * HIDDEN + j];
        s += v; q += v * v;
    }
    float mu = s * (1.f / BATCH);
    float var = q * (1.f / BATCH) - mu * mu;
    float rs = rsqrtf(var + 1e-5f);
    float aj = gamma[j] * rs;
    a[j] = aj;
    bb[j] = beta[j] - mu * aj;
}

// ---------------- FC(1024->1) + sigmoid, one wave per batch row ----------------
__global__ void k_fc(const float* __restrict__ h, const float* __restrict__ a, const float* __restrict__ bb,
                     const float* __restrict__ fcW, const float* __restrict__ fcb, float* __restrict__ out)
{
    int b = blockIdx.x;
    int lane = threadIdx.x;
    float s = 0.f;
    for (int j = lane; j < HIDDEN; j += 64)
        s += (h[(size_t)b * HIDDEN + j] * a[j] + bb[j]) * fcW[j];
#pragma unroll
    for (int m = 32; m; m >>= 1) s += __shfl_xor(s, m, 64);
    if (lane == 0) out[b] = 1.f / (1.f + __expf(-(s + fcb[0])));
}

// ---------------- driver ----------------
extern "C" void kernel_launch(void* const* d_in, const int* in_sizes, int n_in,
                              void* d_out, int out_size, void* d_ws, size_t ws_size,
                              hipStream_t stream)
{
    const float* x = (const float*)d_in[0];
    const float* W_ih[3] = {(const float*)d_in[1], (const float*)d_in[5], (const float*)d_in[9]};
    const float* W_hh[3] = {(const float*)d_in[2], (const float*)d_in[6], (const float*)d_in[10]};
    const float* b_ih[3] = {(const float*)d_in[3], (const float*)d_in[7], (const float*)d_in[11]};
    const float* b_hh[3] = {(const float*)d_in[4], (const float*)d_in[8], (const float*)d_in[12]};
    const float* gamma = (const float*)d_in[13];
    const float* beta  = (const float*)d_in[14];
    const float* fcW   = (const float*)d_in[15];
    const float* fcb   = (const float*)d_in[16];

    char* ws = (char*)d_ws;
    size_t off = 0;
    auto alloc = [&](size_t bytes) -> void* {
        void* p = ws + off;
        off = (off + bytes + 255) & ~(size_t)255;
        return p;
    };
    unsigned short* wih[3]; unsigned short* whh[3];
    wih[0] = (unsigned short*)alloc((size_t)GATES * FEAT * 2);
    whh[0] = (unsigned short*)alloc((size_t)GATES * HIDDEN * 2);
    wih[1] = (unsigned short*)alloc((size_t)GATES * HIDDEN * 2);
    whh[1] = (unsigned short*)alloc((size_t)GATES * HIDDEN * 2);
    wih[2] = (unsigned short*)alloc((size_t)GATES * HIDDEN * 2);
    whh[2] = (unsigned short*)alloc((size_t)GATES * HIDDEN * 2);
    unsigned short* xbf   = (unsigned short*)alloc((size_t)SEQ * BATCH * FEAT * 2);
    unsigned short* hseqA = (unsigned short*)alloc((size_t)SEQ * BATCH * HIDDEN * 2);
    unsigned short* hseqB = (unsigned short*)alloc((size_t)SEQ * BATCH * HIDDEN * 2);
    unsigned short* gx    = (unsigned short*)alloc((size_t)CHUNK_T * BATCH * GATES * 2);
    float* gh = (float*)alloc((size_t)BATCH * GATES * 4);
    float* hf = (float*)alloc((size_t)BATCH * HIDDEN * 4);
    float* abuf = (float*)alloc(HIDDEN * 4);
    float* bbuf = (float*)alloc(HIDDEN * 4);

    // weights -> bf16 (every call: kernel_launch must be stateless)
    k_convert<<<(GATES * FEAT + 255) / 256, 256, 0, stream>>>(W_ih[0], wih[0], GATES * FEAT);
    for (int L = 0; L < 3; ++L) {
        k_convert<<<(GATES * HIDDEN + 255) / 256, 256, 0, stream>>>(W_hh[L], whh[L], GATES * HIDDEN);
        if (L) k_convert<<<(GATES * HIDDEN + 255) / 256, 256, 0, stream>>>(W_ih[L], wih[L], GATES * HIDDEN);
    }
    k_xpose<<<(BATCH * SEQ * FEAT + 255) / 256, 256, 0, stream>>>(x, xbf);

    const unsigned short* inseq = xbf;
    unsigned short* outseq = hseqA;
    for (int L = 0; L < 3; ++L) {
        int Kin = (L == 0) ? FEAT : HIDDEN;
        hipMemsetAsync(hf, 0, (size_t)BATCH * HIDDEN * 4, stream);   // h0 = 0
        for (int c = 0; c < SEQ / CHUNK_T; ++c) {
            // gates_x for this chunk: M = CHUNK_T*BATCH = 8192, N = 3072, K = Kin
            dim3 g1(GATES / 128, (CHUNK_T * BATCH) / 128);
            k_gemm_bt<128, 128, 64, true><<<g1, 256, 0, stream>>>(
                inseq + (size_t)c * CHUNK_T * BATCH * Kin, wih[L], b_ih[L], gx, Kin, GATES);
            for (int tt = 0; tt < CHUNK_T; ++tt) {
                int t = c * CHUNK_T + tt;
                if (t > 0) {   // t==0: h=0 -> gh=0, skip the GEMM entirely
                    dim3 g2(GATES / 64, BATCH / 64);
                    k_gemm_bt<64, 64, 64, false><<<g2, 256, 0, stream>>>(
                        outseq + (size_t)(t - 1) * BATCH * HIDDEN, whh[L], nullptr, gh, HIDDEN, GATES);
                }
                k_gru_elem<<<BATCH * HIDDEN / 256, 256, 0, stream>>>(
                    gx, gh, b_hh[L], hf, outseq + (size_t)t * BATCH * HIDDEN, tt, t == 0);
            }
        }
        inseq = outseq;
        outseq = (outseq == hseqA) ? hseqB : hseqA;
    }

    k_bn_stats<<<HIDDEN / 256, 256, 0, stream>>>(hf, gamma, beta, abuf, bbuf);
    k_fc<<<BATCH, 64, 0, stream>>>(hf, abuf, bbuf, fcW, fcb, (float*)d_out);
}